// Round 2
// baseline (1095.692 us; speedup 1.0000x reference)
//
#include <hip/hip_runtime.h>
#include <hip/hip_bf16.h>
#include <math.h>

#define Hh 48
#define Ww 160
#define NP 7680      // H*W
#define NCHUNK 4
#define CHSZ (NP / NCHUNK) // 1920
#define SORTN 8192

using bf16 = __hip_bfloat16;

__device__ __forceinline__ float bfdec(unsigned short u) {
  return __uint_as_float(((unsigned)u) << 16);
}
__device__ __forceinline__ float ldany(const void* p, int i, int isbf) {
  return isbf ? bfdec(((const unsigned short*)p)[i]) : ((const float*)p)[i];
}

__device__ __forceinline__ int mapidx(int i, int n, int mode) {
  if (mode == 0) return i < 0 ? 0 : (i >= n ? n - 1 : i);       // edge
  return i < 0 ? -i : (i >= n ? 2 * n - 2 - i : i);             // reflect
}

__device__ __forceinline__ float act_apply(float v, int act) {
  if (act == 1) return v > 0.f ? v : expm1f(v);                  // elu
  if (act == 2) {                                                // gelu (tanh approx)
    float c = v + 0.044715f * v * v * v;
    return 0.5f * v * (1.f + tanhf(0.7978845608028654f * c));
  }
  return v;
}

// ---------------- dtype sniffer ----------------
// Sample 2048 16-bit halves of fl_w1 (~N(0,0.05^2)). If data is bf16, ~98%
// decode into (1e-3, 0.5); if fp32, the low halves have random exponents -> ~51%.
__global__ __launch_bounds__(256) void sniff_k(const unsigned short* __restrict__ w,
                                               int* __restrict__ flag) {
  __shared__ int cnt[256];
  int c = 0;
  for (int i = threadIdx.x; i < 2048; i += 256) {
    float a = fabsf(bfdec(w[i]));
    if (a > 1e-3f && a < 0.5f) c++;
  }
  cnt[threadIdx.x] = c;
  __syncthreads();
  for (int s = 128; s > 0; s >>= 1) {
    if (threadIdx.x < s) cnt[threadIdx.x] += cnt[threadIdx.x + s];
    __syncthreads();
  }
  if (threadIdx.x == 0) flag[0] = (cnt[0] > 1536) ? 1 : 0;
}

// ---------------- generic convert to f32 ----------------
__global__ __launch_bounds__(256) void cvt_k(const int* __restrict__ flag,
    const void* __restrict__ src, float* __restrict__ dst, int n) {
  int i = blockIdx.x * 256 + threadIdx.x;
  if (i >= n) return;
  dst[i] = ldany(src, i, *flag);
}

// small tensors packed into one buffer:
// invK@0(16) K@16(16) rw2@32(288) rb2@320(4) sw2@324(162) sb2@486(3) ow2@489(18) ob2@507(1)
__global__ __launch_bounds__(512) void cvt_small_k(const int* __restrict__ flag,
    const void* invK, const void* K, const void* rw2, const void* rb2,
    const void* sw2, const void* sb2, const void* ow2, const void* ob2,
    float* __restrict__ dst) {
  int i = threadIdx.x;
  int f = *flag;
  const void* src; int off;
  if (i < 16)       { src = invK; off = i; }
  else if (i < 32)  { src = K;    off = i - 16; }
  else if (i < 320) { src = rw2;  off = i - 32; }
  else if (i < 324) { src = rb2;  off = i - 320; }
  else if (i < 486) { src = sw2;  off = i - 324; }
  else if (i < 489) { src = sb2;  off = i - 486; }
  else if (i < 507) { src = ow2;  off = i - 489; }
  else if (i < 508) { src = ob2;  off = i - 507; }
  else return;
  dst[i] = ldany(src, off, f);
}

// ---------------- weight repack: [pairs][9] -> f32 [pairs][12] ----------------
__global__ __launch_bounds__(256) void repack_w_k(const int* __restrict__ flag,
    const void* __restrict__ src, float* __restrict__ dst, int npairs) {
  int i = blockIdx.x * 256 + threadIdx.x;
  if (i >= npairs * 12) return;
  int pair = i / 12, k = i - pair * 12;
  dst[i] = (k < 9) ? ldany(src, pair * 9 + k, *flag) : 0.f;
}

// ---------------- bias concat/upcast ----------------
// layout: [0,16) head1 (rot8,scl6,opa2); [16,144) fl_b1; [144,208) fl_b2; [208,336) fr_b
__global__ __launch_bounds__(512) void bias_concat_k(const int* __restrict__ flag,
    const void* rb1, const void* sb1, const void* ob1, const void* fb1,
    const void* fb2, const void* frb, float* __restrict__ dst) {
  int i = threadIdx.x;
  int f = *flag;
  if (i < 8) dst[i] = ldany(rb1, i, f);
  else if (i < 14) dst[i] = ldany(sb1, i - 8, f);
  else if (i < 16) dst[i] = ldany(ob1, i - 14, f);
  else if (i < 144) dst[i] = ldany(fb1, i - 16, f);
  else if (i < 208) dst[i] = ldany(fb2, i - 144, f);
  else if (i < 336) dst[i] = ldany(frb, i - 208, f);
}

// ---------------- tiled direct 3x3 conv (f32 in; f32 or flag-dtype out) ----------------
// block 256 = 64 couts x 4 w-groups of 8; tile = 32 w, 1 h; grid (5, 48, Cout/64)
template<bool FINAL>
__global__ __launch_bounds__(256) void conv_tiled_k(const float* __restrict__ x,
    const float* __restrict__ wp, const float* __restrict__ bias, void* __restrict__ out,
    const int* __restrict__ flag, int Cin, int Cout, int padmode, int act) {
  __shared__ float sx[8][3][36];
  int h = blockIdx.y;
  int w0 = blockIdx.x * 32;
  int coL = threadIdx.x & 63;
  int co = blockIdx.z * 64 + coL;
  int wg = threadIdx.x >> 6;
  int wl = wg * 8;
  bool active = co < Cout;
  int coc = active ? co : (Cout - 1);
  float acc[8];
#pragma unroll
  for (int i = 0; i < 8; i++) acc[i] = 0.f;
  int rows[3];
#pragma unroll
  for (int r = 0; r < 3; r++) rows[r] = mapidx(h + r - 1, Hh, padmode);
  for (int ci0 = 0; ci0 < Cin; ci0 += 8) {
    __syncthreads();
    for (int idx = threadIdx.x; idx < 816; idx += 256) {
      int ci = idx / 102; int rem = idx - ci * 102;
      int r = rem / 34;   int wi = rem - r * 34;
      int wwg = mapidx(w0 + wi - 1, Ww, padmode);
      sx[ci][r][wi] = x[((size_t)(ci0 + ci) * Hh + rows[r]) * Ww + wwg];
    }
    __syncthreads();
    const float* wb = wp + (size_t)(coc * Cin + ci0) * 12;
    for (int ci = 0; ci < 8; ci++) {
      const float4* wv = (const float4*)(wb + ci * 12);
      float4 wA = wv[0], wB = wv[1], wC = wv[2];
      float wk[9] = {wA.x, wA.y, wA.z, wA.w, wB.x, wB.y, wB.z, wB.w, wC.x};
#pragma unroll
      for (int r = 0; r < 3; r++) {
        float rv[10];
#pragma unroll
        for (int q = 0; q < 10; q++) rv[q] = sx[ci][r][wl + q];
#pragma unroll
        for (int pxi = 0; pxi < 8; pxi++)
          acc[pxi] = fmaf(wk[r * 3], rv[pxi],
                     fmaf(wk[r * 3 + 1], rv[pxi + 1],
                     fmaf(wk[r * 3 + 2], rv[pxi + 2], acc[pxi])));
      }
    }
  }
  if (active) {
    float bv = bias[co];
    int isbf = FINAL ? *flag : 0;
#pragma unroll
    for (int pxi = 0; pxi < 8; pxi++) {
      float v = act_apply(acc[pxi] + bv, act);
      size_t oi = ((size_t)co * Hh + h) * Ww + w0 + wl + pxi;
      if (FINAL && isbf) ((bf16*)out)[oi] = __float2bfloat16(v);
      else ((float*)out)[oi] = v;
    }
  }
}

// ---------------- head2 + per-gaussian prep ----------------
__global__ __launch_bounds__(128) void head2_prep_k(const float* __restrict__ h1,
    const float* __restrict__ smallf, const float* __restrict__ dispf,
    float* __restrict__ params) {
  const float* invK = smallf;
  const float* Km   = smallf + 16;
  const float* rw2  = smallf + 32;
  const float* rb2  = smallf + 320;
  const float* sw2  = smallf + 324;
  const float* sb2  = smallf + 486;
  const float* ow2  = smallf + 489;
  const float* ob2  = smallf + 507;
  int p = blockIdx.x * 128 + threadIdx.x;
  if (p >= NP) return;
  int hh = p / Ww, ww = p - hh * Ww;
  float racc[4], sacc[3], oacc;
#pragma unroll
  for (int i = 0; i < 4; i++) racc[i] = rb2[i];
#pragma unroll
  for (int i = 0; i < 3; i++) sacc[i] = sb2[i];
  oacc = ob2[0];
  for (int ci = 0; ci < 16; ci++) {
    float t9[9];
#pragma unroll
    for (int r = 0; r < 3; r++) {
      int rr = mapidx(hh + r - 1, Hh, 0);
#pragma unroll
      for (int s = 0; s < 3; s++) {
        int cc = mapidx(ww + s - 1, Ww, 0);
        t9[r * 3 + s] = h1[(size_t)ci * NP + rr * Ww + cc];
      }
    }
    if (ci < 8) {
      for (int co = 0; co < 4; co++)
#pragma unroll
        for (int k = 0; k < 9; k++)
          racc[co] = fmaf(t9[k], rw2[(co * 8 + ci) * 9 + k], racc[co]);
    } else if (ci < 14) {
      int c2 = ci - 8;
      for (int co = 0; co < 3; co++)
#pragma unroll
        for (int k = 0; k < 9; k++)
          sacc[co] = fmaf(t9[k], sw2[(co * 6 + c2) * 9 + k], sacc[co]);
    } else {
      int c2 = ci - 14;
#pragma unroll
      for (int k = 0; k < 9; k++)
        oacc = fmaf(t9[k], ow2[c2 * 9 + k], oacc);
    }
  }
  float nq = sqrtf(racc[0]*racc[0] + racc[1]*racc[1] + racc[2]*racc[2] + racc[3]*racc[3]);
  nq = fmaxf(nq, 1e-12f);
  float qw = racc[0] / nq, qx = racc[1] / nq, qy = racc[2] / nq, qz = racc[3] / nq;
  float s0 = fabsf(sacc[0]), s1 = fabsf(sacc[1]), s2 = fabsf(sacc[2]);
  float opa = 1.f / (1.f + __expf(-oacc));
  float d = dispf[p];
  float scaled = 0.01f + 9.99f * d;                 // 1/MAX + (1/MIN-1/MAX)*disp
  float depth = fminf(fmaxf(1.f / scaled, 0.1f), 100.f);
  float M00 = invK[0], M01 = invK[1], M02 = invK[2];
  float M10 = invK[4], M11 = invK[5], M12 = invK[6];
  float M20 = invK[8], M21 = invK[9], M22 = invK[10];
  float gxf = (float)ww, gyf = (float)hh;
  float X = (M00 * gxf + M01 * gyf + M02) * depth;
  float Y = (M10 * gxf + M11 * gyf + M12) * depth;
  float Z = (M20 * gxf + M21 * gyf + M22) * depth;
  float fxk = Km[0], fyk = Km[5];
  float cxk = Km[2], cyk = Km[6];
  float u = fxk * X / Z + cxk;
  float v = fyk * Y / Z + cyk;
  float R00 = 1.f - 2.f*(qy*qy + qz*qz), R01 = 2.f*(qx*qy - qw*qz), R02 = 2.f*(qx*qz + qw*qy);
  float R10 = 2.f*(qx*qy + qw*qz), R11 = 1.f - 2.f*(qx*qx + qz*qz), R12 = 2.f*(qy*qz - qw*qx);
  float R20 = 2.f*(qx*qz - qw*qy), R21 = 2.f*(qy*qz + qw*qx), R22 = 1.f - 2.f*(qx*qx + qy*qy);
  float M0a = R00*s0, M0b = R01*s1, M0c = R02*s2;
  float M1a = R10*s0, M1b = R11*s1, M1c = R12*s2;
  float M2a = R20*s0, M2b = R21*s1, M2c = R22*s2;
  float S00 = M0a*M0a + M0b*M0b + M0c*M0c;
  float S01 = M0a*M1a + M0b*M1b + M0c*M1c;
  float S02 = M0a*M2a + M0b*M2b + M0c*M2c;
  float S11 = M1a*M1a + M1b*M1b + M1c*M1c;
  float S12 = M1a*M2a + M1b*M2b + M1c*M2c;
  float S22 = M2a*M2a + M2b*M2b + M2c*M2c;
  float iz = 1.f / Z;
  float j00 = fxk * iz, j02 = -fxk * X * iz * iz;
  float j11 = fyk * iz, j12 = -fyk * Y * iz * iz;
  float c00 = j00*j00*S00 + 2.f*j00*j02*S02 + j02*j02*S22 + 0.3f;
  float c01 = j00*j11*S01 + j00*j12*S02 + j02*j11*S12 + j02*j12*S22;
  float c11 = j11*j11*S11 + 2.f*j11*j12*S12 + j12*j12*S22 + 0.3f;
  float det = c00 * c11 - c01 * c01;
  float idet = 1.f / det;
  float* pr = params + (size_t)p * 8;
  pr[0] = u; pr[1] = v; pr[2] = c11 * idet; pr[3] = -c01 * idet;
  pr[4] = c00 * idet; pr[5] = opa; pr[6] = Z; pr[7] = 0.f;
}

// ---------------- bitonic stable sort by z ----------------
__global__ __launch_bounds__(1024) void sort_k(const float* __restrict__ params,
                                               unsigned long long* __restrict__ keys) {
  __shared__ unsigned long long sk[SORTN];
  int tid = threadIdx.x;
  for (int i = tid; i < SORTN; i += 1024) {
    if (i < NP) {
      unsigned zu = __float_as_uint(params[(size_t)i * 8 + 6]);  // z > 0 -> bits monotone
      sk[i] = ((unsigned long long)zu << 32) | (unsigned)i;      // idx low bits = stable
    } else sk[i] = ~0ULL;
  }
  __syncthreads();
  for (int k = 2; k <= SORTN; k <<= 1) {
    for (int j = k >> 1; j > 0; j >>= 1) {
      for (int i = tid; i < SORTN; i += 1024) {
        int l = i ^ j;
        if (l > i) {
          unsigned long long a = sk[i], b = sk[l];
          bool up = ((i & k) == 0);
          if ((a > b) == up) { sk[i] = b; sk[l] = a; }
        }
      }
      __syncthreads();
    }
  }
  for (int i = tid; i < NP; i += 1024) keys[i] = sk[i];
}

// ---------------- gather into sorted order ----------------
__global__ __launch_bounds__(256) void gather_k(const unsigned long long* __restrict__ keys,
    const float* __restrict__ params, const float* __restrict__ t2,
    float* __restrict__ params_s, float* __restrict__ feat_s) {
  int gid = blockIdx.x * 256 + threadIdx.x;   // NP*64
  int n = gid >> 6, c = gid & 63;
  int orig = (int)(keys[n] & 0xFFFFFFFFu);
  feat_s[gid] = t2[(size_t)c * NP + orig];
  if (c < 8) params_s[(n << 3) + c] = params[((size_t)orig << 3) + c];
}

// ---------------- chunked rasterizer ----------------
__global__ __launch_bounds__(128) void raster_k(const float* __restrict__ params_s,
    const float* __restrict__ feat_s, float* __restrict__ partial, float* __restrict__ tch) {
  int p = blockIdx.x * 128 + threadIdx.x;
  int ch = blockIdx.y;
  float px = (float)(p % Ww), py = (float)(p / Ww);
  float4 acc[16];
#pragma unroll
  for (int q = 0; q < 16; q++) acc[q] = make_float4(0.f, 0.f, 0.f, 0.f);
  float T = 1.f;
  int g0 = ch * CHSZ;
  for (int n = g0; n < g0 + CHSZ; n++) {
    const float4* prm = (const float4*)(params_s + ((size_t)n << 3));
    float4 pa = prm[0];  // u v A B
    float4 pb = prm[1];  // C opa z pad
    float dx = px - pa.x, dy = py - pa.y;
    float power = -0.5f * (pa.z * dx * dx + pb.x * dy * dy) - pa.w * dx * dy;
    float al = (power <= 0.f) ? fminf(pb.y * __expf(power), 0.99f) : 0.f;
    float wgt = al * T;
    T *= 1.f - al;
    if (__ballot(wgt > 0.f)) {   // wave-level footprint skip
      const float4* fr = (const float4*)(feat_s + ((size_t)n << 6));
#pragma unroll
      for (int q = 0; q < 16; q++) {
        float4 f = fr[q];
        acc[q].x = fmaf(wgt, f.x, acc[q].x);
        acc[q].y = fmaf(wgt, f.y, acc[q].y);
        acc[q].z = fmaf(wgt, f.z, acc[q].z);
        acc[q].w = fmaf(wgt, f.w, acc[q].w);
      }
    }
  }
#pragma unroll
  for (int q = 0; q < 16; q++) {
    partial[((size_t)ch * 64 + q * 4 + 0) * NP + p] = acc[q].x;
    partial[((size_t)ch * 64 + q * 4 + 1) * NP + p] = acc[q].y;
    partial[((size_t)ch * 64 + q * 4 + 2) * NP + p] = acc[q].z;
    partial[((size_t)ch * 64 + q * 4 + 3) * NP + p] = acc[q].w;
  }
  tch[(size_t)ch * NP + p] = T;
}

// ---------------- combine chunks with prefix transmittance ----------------
__global__ __launch_bounds__(256) void combine_k(const float* __restrict__ partial,
    const float* __restrict__ tch, float* __restrict__ lev) {
  int gid = blockIdx.x * 256 + threadIdx.x;   // 64*NP, gid = c*NP + p
  int c = gid / NP, p = gid - c * NP;
  float T = 1.f, s = 0.f;
  for (int ch = 0; ch < NCHUNK; ch++) {
    s = fmaf(T, partial[((size_t)ch * 64 + c) * NP + p], s);
    T *= tch[(size_t)ch * NP + p];
  }
  lev[gid] = s;
}

extern "C" void kernel_launch(void* const* d_in, const int* in_sizes, int n_in,
                              void* d_out, int out_size, void* d_ws, size_t ws_size,
                              hipStream_t stream) {
  (void)in_sizes; (void)n_in; (void)out_size; (void)ws_size;
  const void* init_feature = d_in[0];
  const void* disp   = d_in[1];
  const void* invK   = d_in[2];
  const void* Km     = d_in[3];
  const void* rot_w1 = d_in[4];
  const void* rot_b1 = d_in[5];
  const void* rot_w2 = d_in[6];
  const void* rot_b2 = d_in[7];
  const void* scl_w1 = d_in[8];
  const void* scl_b1 = d_in[9];
  const void* scl_w2 = d_in[10];
  const void* scl_b2 = d_in[11];
  const void* opa_w1 = d_in[12];
  const void* opa_b1 = d_in[13];
  const void* opa_w2 = d_in[14];
  const void* opa_b2 = d_in[15];
  const void* fl_w1  = d_in[16];
  const void* fl_b1  = d_in[17];
  const void* fl_w2  = d_in[18];
  const void* fl_b2  = d_in[19];
  const void* fr_w   = d_in[20];
  const void* fr_b   = d_in[21];

  float* wsf = (float*)d_ws;
  // layout (floats); total 4,158,992 f = 16.64 MB
  int*   flag    = (int*)wsf;                   // @0 (16 f reserved)
  float* xf      = wsf + 16;                    // 983040
  float* t1      = wsf + 983056;                // 983040
  float* h1      = wsf + 1966096;               // 122880
  float* t2      = wsf + 2088976;               // 491520
  float* params  = wsf + 2580496;               // 61440
  unsigned long long* keys = (unsigned long long*)(wsf + 2641936); // 15360 f
  float* smallf  = wsf + 2657296;               // 512
  float* dispf   = wsf + 2657808;               // 7680
  float* wp_fl1  = wsf + 2665488;               // 196608
  float* wp_fl2  = wsf + 2862096;               // 98304
  float* wp_fr   = wsf + 2960400;               // 98304
  float* wp_h1   = wsf + 3058704;               // 24576
  float* biasf   = wsf + 3083280;               // 512
  float* params_s= wsf + 3083792;               // 61440
  float* feat_s  = wsf + 3145232;               // 491520
  float* tch     = wsf + 3636752;               // 30720
  float* lev     = wsf + 3667472;               // 491520
  float* partial = xf;   // aliases [xf|t1] = 1,966,080 f; both dead before raster

  // dtype sniff, then convert everything to f32
  sniff_k<<<1, 256, 0, stream>>>((const unsigned short*)fl_w1, flag);
  cvt_k<<<3840, 256, 0, stream>>>(flag, init_feature, xf, 983040);
  cvt_k<<<30, 256, 0, stream>>>(flag, disp, dispf, 7680);
  cvt_small_k<<<1, 512, 0, stream>>>(flag, invK, Km, rot_w2, rot_b2,
                                     scl_w2, scl_b2, opa_w2, opa_b2, smallf);
  repack_w_k<<<768, 256, 0, stream>>>(flag, fl_w1, wp_fl1, 16384);
  repack_w_k<<<384, 256, 0, stream>>>(flag, fl_w2, wp_fl2, 8192);
  repack_w_k<<<384, 256, 0, stream>>>(flag, fr_w, wp_fr, 8192);
  repack_w_k<<<48, 256, 0, stream>>>(flag, rot_w1, wp_h1, 1024);
  repack_w_k<<<36, 256, 0, stream>>>(flag, scl_w1, wp_h1 + 1024 * 12, 768);
  repack_w_k<<<12, 256, 0, stream>>>(flag, opa_w1, wp_h1 + 1792 * 12, 256);
  bias_concat_k<<<1, 512, 0, stream>>>(flag, rot_b1, scl_b1, opa_b1, fl_b1, fl_b2, fr_b, biasf);

  // heads first conv (16 ch, edge, gelu)
  conv_tiled_k<false><<<dim3(5, 48, 1), 256, 0, stream>>>(xf, wp_h1, biasf, h1, flag, 128, 16, 0, 2);
  // gs_feat chain (reflect, elu)
  conv_tiled_k<false><<<dim3(5, 48, 2), 256, 0, stream>>>(xf, wp_fl1, biasf + 16, t1, flag, 128, 128, 1, 1);
  conv_tiled_k<false><<<dim3(5, 48, 1), 256, 0, stream>>>(t1, wp_fl2, biasf + 144, t2, flag, 128, 64, 1, 1);
  // heads second conv + gaussian prep
  head2_prep_k<<<60, 128, 0, stream>>>(h1, smallf, dispf, params);
  // stable sort by depth, gather
  sort_k<<<1, 1024, 0, stream>>>(params, keys);
  gather_k<<<(NP * 64) / 256, 256, 0, stream>>>(keys, params, t2, params_s, feat_s);
  // rasterize (chunked; partial aliases dead xf|t1) + combine
  raster_k<<<dim3(NP / 128, NCHUNK), 128, 0, stream>>>(params_s, feat_s, partial, tch);
  combine_k<<<(NP * 64) / 256, 256, 0, stream>>>(partial, tch, lev);
  // final conv (reflect, elu) -> out (dtype per flag)
  conv_tiled_k<true><<<dim3(5, 48, 2), 256, 0, stream>>>(lev, wp_fr, biasf + 208, d_out, flag, 64, 128, 1, 1);
}

// Round 3
// 837.058 us; speedup vs baseline: 1.3090x; 1.3090x over previous
//
#include <hip/hip_runtime.h>
#include <hip/hip_bf16.h>
#include <math.h>

#define Hh 48
#define Ww 160
#define NP 7680      // H*W
#define NCHUNK 5
#define CHSZ (NP / NCHUNK) // 1536
#define SORTN 8192

using bf16 = __hip_bfloat16;

__device__ __forceinline__ float bfdec(unsigned short u) {
  return __uint_as_float(((unsigned)u) << 16);
}
__device__ __forceinline__ float ldany(const void* p, size_t i, int isbf) {
  return isbf ? bfdec(((const unsigned short*)p)[i]) : ((const float*)p)[i];
}

__device__ __forceinline__ int mapidx(int i, int n, int mode) {
  if (mode == 0) return i < 0 ? 0 : (i >= n ? n - 1 : i);       // edge
  return i < 0 ? -i : (i >= n ? 2 * n - 2 - i : i);             // reflect
}

__device__ __forceinline__ float act_apply(float v, int act) {
  if (act == 1) return v > 0.f ? v : expm1f(v);                  // elu
  if (act == 2) {                                                // gelu (tanh approx)
    float c = v + 0.044715f * v * v * v;
    return 0.5f * v * (1.f + tanhf(0.7978845608028654f * c));
  }
  return v;
}

// ---------------- dtype sniffer ----------------
__global__ __launch_bounds__(256) void sniff_k(const unsigned short* __restrict__ w,
                                               int* __restrict__ flag) {
  __shared__ int cnt[256];
  int c = 0;
  for (int i = threadIdx.x; i < 2048; i += 256) {
    float a = fabsf(bfdec(w[i]));
    if (a > 1e-3f && a < 0.5f) c++;
  }
  cnt[threadIdx.x] = c;
  __syncthreads();
  for (int s = 128; s > 0; s >>= 1) {
    if (threadIdx.x < s) cnt[threadIdx.x] += cnt[threadIdx.x + s];
    __syncthreads();
  }
  if (threadIdx.x == 0) flag[0] = (cnt[0] > 1536) ? 1 : 0;
}

// ---------------- generic convert to f32 ----------------
__global__ __launch_bounds__(256) void cvt_k(const int* __restrict__ flag,
    const void* __restrict__ src, float* __restrict__ dst, int n) {
  int i = blockIdx.x * 256 + threadIdx.x;
  if (i >= n) return;
  dst[i] = ldany(src, i, *flag);
}

// small tensors packed: invK@0(16) K@16(16) rw2@32(288) rb2@320(4) sw2@324(162)
// sb2@486(3) ow2@489(18) ob2@507(1)
__global__ __launch_bounds__(512) void cvt_small_k(const int* __restrict__ flag,
    const void* invK, const void* K, const void* rw2, const void* rb2,
    const void* sw2, const void* sb2, const void* ow2, const void* ob2,
    float* __restrict__ dst) {
  int i = threadIdx.x;
  int f = *flag;
  const void* src; int off;
  if (i < 16)       { src = invK; off = i; }
  else if (i < 32)  { src = K;    off = i - 16; }
  else if (i < 320) { src = rw2;  off = i - 32; }
  else if (i < 324) { src = rb2;  off = i - 320; }
  else if (i < 486) { src = sw2;  off = i - 324; }
  else if (i < 489) { src = sb2;  off = i - 486; }
  else if (i < 507) { src = ow2;  off = i - 489; }
  else if (i < 508) { src = ob2;  off = i - 507; }
  else return;
  dst[i] = ldany(src, off, f);
}

// ---------------- weight repack: [co][ci][3][3] -> [ci*9+k][CoutTot] ----------------
__global__ __launch_bounds__(256) void repack_w_k(const int* __restrict__ flag,
    const void* __restrict__ src, float* __restrict__ dst,
    int Cin9, int CoutHead, int CoutTot, int co_off) {
  int i = blockIdx.x * 256 + threadIdx.x;
  if (i >= CoutHead * Cin9) return;
  int co = i / Cin9, rem = i - co * Cin9;
  dst[(size_t)rem * CoutTot + co_off + co] = ldany(src, i, *flag);
}

// ---------------- bias concat ----------------
// [0,16) head1 (rot8,scl6,opa2); [16,144) fl_b1; [144,208) fl_b2; [208,336) fr_b
__global__ __launch_bounds__(512) void bias_concat_k(const int* __restrict__ flag,
    const void* rb1, const void* sb1, const void* ob1, const void* fb1,
    const void* fb2, const void* frb, float* __restrict__ dst) {
  int i = threadIdx.x;
  int f = *flag;
  if (i < 8) dst[i] = ldany(rb1, i, f);
  else if (i < 14) dst[i] = ldany(sb1, i - 8, f);
  else if (i < 16) dst[i] = ldany(ob1, i - 14, f);
  else if (i < 144) dst[i] = ldany(fb1, i - 16, f);
  else if (i < 208) dst[i] = ldany(fb2, i - 144, f);
  else if (i < 336) dst[i] = ldany(frb, i - 208, f);
}

// ---------------- tiled direct 3x3 conv ----------------
// block 256 = COB couts x (256/COB) w-groups of PXT px; tile = 32 w, 1 h
// weights: [ci*9+k][Cout] (lane-coalesced). grid (5, 48, Cout/COB)
template<bool FIRST, bool FINAL, bool TRANS, int COB, int PXT>
__global__ __launch_bounds__(256) void conv_tiled_k(const void* __restrict__ xv,
    const float* __restrict__ wp, const float* __restrict__ bias, void* __restrict__ out,
    const int* __restrict__ flag, int Cin, int Cout, int padmode, int act) {
  __shared__ float sx[8][3][36];
  const int h = blockIdx.y;
  const int w0 = blockIdx.x * 32;
  const int coL = threadIdx.x & (COB - 1);
  const int co = blockIdx.z * COB + coL;
  const int wg = threadIdx.x / COB;
  const int wl = wg * PXT;
  const int isbf = FIRST ? *flag : 0;
  float acc[PXT];
#pragma unroll
  for (int i = 0; i < PXT; i++) acc[i] = 0.f;
  int rows[3];
#pragma unroll
  for (int r = 0; r < 3; r++) rows[r] = mapidx(h + r - 1, Hh, padmode);
  for (int ci0 = 0; ci0 < Cin; ci0 += 8) {
    __syncthreads();
    for (int idx = threadIdx.x; idx < 816; idx += 256) {
      int ci = idx / 102; int rem = idx - ci * 102;
      int r = rem / 34;   int wi = rem - r * 34;
      int wwg = mapidx(w0 + wi - 1, Ww, padmode);
      sx[ci][r][wi] = ldany(xv, ((size_t)(ci0 + ci) * Hh + rows[r]) * Ww + wwg, isbf);
    }
    __syncthreads();
#pragma unroll
    for (int ci = 0; ci < 8; ci++) {
      float wk[9];
      const float* wb = wp + (size_t)((ci0 + ci) * 9) * Cout + co;
#pragma unroll
      for (int k = 0; k < 9; k++) wk[k] = wb[(size_t)k * Cout];
#pragma unroll
      for (int r = 0; r < 3; r++) {
        float rv[PXT + 2];
        if constexpr (PXT == 8) {
          const float4* sv = (const float4*)&sx[ci][r][0];
          float4 a = sv[wl / 4], b = sv[wl / 4 + 1], c = sv[wl / 4 + 2];
          rv[0]=a.x; rv[1]=a.y; rv[2]=a.z; rv[3]=a.w;
          rv[4]=b.x; rv[5]=b.y; rv[6]=b.z; rv[7]=b.w;
          rv[8]=c.x; rv[9]=c.y;
        } else {
#pragma unroll
          for (int q = 0; q < PXT + 2; q++) rv[q] = sx[ci][r][wl + q];
        }
#pragma unroll
        for (int pxi = 0; pxi < PXT; pxi++)
          acc[pxi] = fmaf(wk[r * 3], rv[pxi],
                     fmaf(wk[r * 3 + 1], rv[pxi + 1],
                     fmaf(wk[r * 3 + 2], rv[pxi + 2], acc[pxi])));
      }
    }
  }
  {
    float bv = bias[co];
    int obf = FINAL ? *flag : 0;
#pragma unroll
    for (int pxi = 0; pxi < PXT; pxi++) {
      float v = act_apply(acc[pxi] + bv, act);
      if (TRANS) {
        ((float*)out)[(size_t)(h * Ww + w0 + wl + pxi) * 64 + co] = v;
      } else {
        size_t oi = ((size_t)co * Hh + h) * Ww + w0 + wl + pxi;
        if (FINAL && obf) ((bf16*)out)[oi] = __float2bfloat16(v);
        else ((float*)out)[oi] = v;
      }
    }
  }
}

// ---------------- head2 + per-gaussian prep ----------------
__global__ __launch_bounds__(128) void head2_prep_k(const float* __restrict__ h1,
    const float* __restrict__ smallf, const float* __restrict__ dispf,
    float* __restrict__ params) {
  const float* invK = smallf;
  const float* Km   = smallf + 16;
  const float* rw2  = smallf + 32;
  const float* rb2  = smallf + 320;
  const float* sw2  = smallf + 324;
  const float* sb2  = smallf + 486;
  const float* ow2  = smallf + 489;
  const float* ob2  = smallf + 507;
  int p = blockIdx.x * 128 + threadIdx.x;
  if (p >= NP) return;
  int hh = p / Ww, ww = p - hh * Ww;
  float racc[4], sacc[3], oacc;
#pragma unroll
  for (int i = 0; i < 4; i++) racc[i] = rb2[i];
#pragma unroll
  for (int i = 0; i < 3; i++) sacc[i] = sb2[i];
  oacc = ob2[0];
  for (int ci = 0; ci < 16; ci++) {
    float t9[9];
#pragma unroll
    for (int r = 0; r < 3; r++) {
      int rr = mapidx(hh + r - 1, Hh, 0);
#pragma unroll
      for (int s = 0; s < 3; s++) {
        int cc = mapidx(ww + s - 1, Ww, 0);
        t9[r * 3 + s] = h1[(size_t)ci * NP + rr * Ww + cc];
      }
    }
    if (ci < 8) {
      for (int co = 0; co < 4; co++)
#pragma unroll
        for (int k = 0; k < 9; k++)
          racc[co] = fmaf(t9[k], rw2[(co * 8 + ci) * 9 + k], racc[co]);
    } else if (ci < 14) {
      int c2 = ci - 8;
      for (int co = 0; co < 3; co++)
#pragma unroll
        for (int k = 0; k < 9; k++)
          sacc[co] = fmaf(t9[k], sw2[(co * 6 + c2) * 9 + k], sacc[co]);
    } else {
      int c2 = ci - 14;
#pragma unroll
      for (int k = 0; k < 9; k++)
        oacc = fmaf(t9[k], ow2[c2 * 9 + k], oacc);
    }
  }
  float nq = sqrtf(racc[0]*racc[0] + racc[1]*racc[1] + racc[2]*racc[2] + racc[3]*racc[3]);
  nq = fmaxf(nq, 1e-12f);
  float qw = racc[0] / nq, qx = racc[1] / nq, qy = racc[2] / nq, qz = racc[3] / nq;
  float s0 = fabsf(sacc[0]), s1 = fabsf(sacc[1]), s2 = fabsf(sacc[2]);
  float opa = 1.f / (1.f + __expf(-oacc));
  float d = dispf[p];
  float scaled = 0.01f + 9.99f * d;
  float depth = fminf(fmaxf(1.f / scaled, 0.1f), 100.f);
  float M00 = invK[0], M01 = invK[1], M02 = invK[2];
  float M10 = invK[4], M11 = invK[5], M12 = invK[6];
  float M20 = invK[8], M21 = invK[9], M22 = invK[10];
  float gxf = (float)ww, gyf = (float)hh;
  float X = (M00 * gxf + M01 * gyf + M02) * depth;
  float Y = (M10 * gxf + M11 * gyf + M12) * depth;
  float Z = (M20 * gxf + M21 * gyf + M22) * depth;
  float fxk = Km[0], fyk = Km[5];
  float cxk = Km[2], cyk = Km[6];
  float u = fxk * X / Z + cxk;
  float v = fyk * Y / Z + cyk;
  float R00 = 1.f - 2.f*(qy*qy + qz*qz), R01 = 2.f*(qx*qy - qw*qz), R02 = 2.f*(qx*qz + qw*qy);
  float R10 = 2.f*(qx*qy + qw*qz), R11 = 1.f - 2.f*(qx*qx + qz*qz), R12 = 2.f*(qy*qz - qw*qx);
  float R20 = 2.f*(qx*qz - qw*qy), R21 = 2.f*(qy*qz + qw*qx), R22 = 1.f - 2.f*(qx*qx + qy*qy);
  float M0a = R00*s0, M0b = R01*s1, M0c = R02*s2;
  float M1a = R10*s0, M1b = R11*s1, M1c = R12*s2;
  float M2a = R20*s0, M2b = R21*s1, M2c = R22*s2;
  float S00 = M0a*M0a + M0b*M0b + M0c*M0c;
  float S01 = M0a*M1a + M0b*M1b + M0c*M1c;
  float S02 = M0a*M2a + M0b*M2b + M0c*M2c;
  float S11 = M1a*M1a + M1b*M1b + M1c*M1c;
  float S12 = M1a*M2a + M1b*M2b + M1c*M2c;
  float S22 = M2a*M2a + M2b*M2b + M2c*M2c;
  float iz = 1.f / Z;
  float j00 = fxk * iz, j02 = -fxk * X * iz * iz;
  float j11 = fyk * iz, j12 = -fyk * Y * iz * iz;
  float c00 = j00*j00*S00 + 2.f*j00*j02*S02 + j02*j02*S22 + 0.3f;
  float c01 = j00*j11*S01 + j00*j12*S02 + j02*j11*S12 + j02*j12*S22;
  float c11 = j11*j11*S11 + 2.f*j11*j12*S12 + j12*j12*S22 + 0.3f;
  float det = c00 * c11 - c01 * c01;
  float idet = 1.f / det;
  float* pr = params + (size_t)p * 8;
  pr[0] = u; pr[1] = v; pr[2] = c11 * idet; pr[3] = -c01 * idet;
  pr[4] = c00 * idet; pr[5] = opa; pr[6] = Z; pr[7] = 0.f;
}

// ---------------- bitonic stable sort by z ----------------
__global__ __launch_bounds__(1024) void sort_k(const float* __restrict__ params,
                                               unsigned long long* __restrict__ keys) {
  __shared__ unsigned long long sk[SORTN];
  int tid = threadIdx.x;
  for (int i = tid; i < SORTN; i += 1024) {
    if (i < NP) {
      unsigned zu = __float_as_uint(params[(size_t)i * 8 + 6]);
      sk[i] = ((unsigned long long)zu << 32) | (unsigned)i;
    } else sk[i] = ~0ULL;
  }
  __syncthreads();
  for (int k = 2; k <= SORTN; k <<= 1) {
    for (int j = k >> 1; j > 0; j >>= 1) {
      for (int i = tid; i < SORTN; i += 1024) {
        int l = i ^ j;
        if (l > i) {
          unsigned long long a = sk[i], b = sk[l];
          bool up = ((i & k) == 0);
          if ((a > b) == up) { sk[i] = b; sk[l] = a; }
        }
      }
      __syncthreads();
    }
  }
  for (int i = tid; i < NP; i += 1024) keys[i] = sk[i];
}

// ---------------- gather into sorted order (t2t is [px][64]) ----------------
__global__ __launch_bounds__(256) void gather_k(const unsigned long long* __restrict__ keys,
    const float* __restrict__ params, const float* __restrict__ t2t,
    float* __restrict__ params_s, float* __restrict__ feat_s) {
  int gid = blockIdx.x * 256 + threadIdx.x;   // NP*64
  int n = gid >> 6, c = gid & 63;
  int orig = (int)(keys[n] & 0xFFFFFFFFu);
  feat_s[gid] = t2t[((size_t)orig << 6) + c];
  if (c < 8) params_s[(n << 3) + c] = params[((size_t)orig << 3) + c];
}

// ---------------- chunked rasterizer, LDS-staged params, feature-split x4 ----------------
// block 256 = 64 px x 4 fgroups of 16 feats; grid (NP/64, NCHUNK)
__global__ __launch_bounds__(256) void raster_k(const float* __restrict__ params_s,
    const float* __restrict__ feat_s, float* __restrict__ partial, float* __restrict__ tch) {
  __shared__ float4 sp4[CHSZ * 2];           // 48 KB
  const int pxl = threadIdx.x & 63;
  const int fg = threadIdx.x >> 6;
  const int p = blockIdx.x * 64 + pxl;
  const int ch = blockIdx.y;
  const int g0 = ch * CHSZ;
  {
    const float4* pv = (const float4*)params_s;
    for (int i = threadIdx.x; i < CHSZ * 2; i += 256) sp4[i] = pv[g0 * 2 + i];
  }
  __syncthreads();
  const float px = (float)(p % Ww), py = (float)(p / Ww);
  float4 acc[4];
#pragma unroll
  for (int q = 0; q < 4; q++) acc[q] = make_float4(0.f, 0.f, 0.f, 0.f);
  float T = 1.f;
  for (int n = 0; n < CHSZ; n++) {
    float4 pa = sp4[n * 2];      // u v A B
    float4 pb = sp4[n * 2 + 1];  // C opa z pad
    float dx = px - pa.x, dy = py - pa.y;
    float power = -0.5f * (pa.z * dx * dx + pb.x * dy * dy) - pa.w * dx * dy;
    float al = (power <= 0.f) ? fminf(pb.y * __expf(power), 0.99f) : 0.f;
    float wgt = al * T;
    T *= 1.f - al;
    if (__any(wgt > 0.f)) {
      const float4* fr = (const float4*)(feat_s + (((size_t)(g0 + n)) << 6)) + fg * 4;
#pragma unroll
      for (int q = 0; q < 4; q++) {
        float4 f = fr[q];
        acc[q].x = fmaf(wgt, f.x, acc[q].x);
        acc[q].y = fmaf(wgt, f.y, acc[q].y);
        acc[q].z = fmaf(wgt, f.z, acc[q].z);
        acc[q].w = fmaf(wgt, f.w, acc[q].w);
      }
    }
  }
  const int cb = fg * 16;
#pragma unroll
  for (int q = 0; q < 4; q++) {
    partial[((size_t)ch * 64 + cb + q * 4 + 0) * NP + p] = acc[q].x;
    partial[((size_t)ch * 64 + cb + q * 4 + 1) * NP + p] = acc[q].y;
    partial[((size_t)ch * 64 + cb + q * 4 + 2) * NP + p] = acc[q].z;
    partial[((size_t)ch * 64 + cb + q * 4 + 3) * NP + p] = acc[q].w;
  }
  if (fg == 0) tch[(size_t)ch * NP + p] = T;
}

// ---------------- combine chunks with prefix transmittance ----------------
__global__ __launch_bounds__(256) void combine_k(const float* __restrict__ partial,
    const float* __restrict__ tch, float* __restrict__ lev) {
  int gid = blockIdx.x * 256 + threadIdx.x;   // 64*NP, gid = c*NP + p
  int c = gid / NP, p = gid - c * NP;
  float T = 1.f, s = 0.f;
  for (int ch = 0; ch < NCHUNK; ch++) {
    s = fmaf(T, partial[((size_t)ch * 64 + c) * NP + p], s);
    T *= tch[(size_t)ch * NP + p];
  }
  lev[gid] = s;
}

extern "C" void kernel_launch(void* const* d_in, const int* in_sizes, int n_in,
                              void* d_out, int out_size, void* d_ws, size_t ws_size,
                              hipStream_t stream) {
  (void)in_sizes; (void)n_in; (void)out_size; (void)ws_size;
  const void* init_feature = d_in[0];
  const void* disp   = d_in[1];
  const void* invK   = d_in[2];
  const void* Km     = d_in[3];
  const void* rot_w1 = d_in[4];
  const void* rot_b1 = d_in[5];
  const void* rot_w2 = d_in[6];
  const void* rot_b2 = d_in[7];
  const void* scl_w1 = d_in[8];
  const void* scl_b1 = d_in[9];
  const void* scl_w2 = d_in[10];
  const void* scl_b2 = d_in[11];
  const void* opa_w1 = d_in[12];
  const void* opa_b1 = d_in[13];
  const void* opa_w2 = d_in[14];
  const void* opa_b2 = d_in[15];
  const void* fl_w1  = d_in[16];
  const void* fl_b1  = d_in[17];
  const void* fl_w2  = d_in[18];
  const void* fl_b2  = d_in[19];
  const void* fr_w   = d_in[20];
  const void* fr_b   = d_in[21];

  float* wsf = (float*)d_ws;
  // ---- persistent region ----
  int*   flag    = (int*)wsf;                   // @0        16
  float* smallf  = wsf + 16;                    // 512
  float* dispf   = wsf + 528;                   // 7680
  float* biasf   = wsf + 8208;                  // 512
  float* wp_h1   = wsf + 8720;                  // 128*9*16  = 18432
  float* wp_fl1  = wsf + 27152;                 // 128*9*128 = 147456
  float* wp_fl2  = wsf + 174608;                // 128*9*64  = 73728
  float* wp_fr   = wsf + 248336;                // 64*9*128  = 73728
  float* params_s= wsf + 322064;                // 61440
  float* feat_s  = wsf + 383504;                // 491520
  float* tch     = wsf + 875024;                // 5*7680 = 38400
  float* lev     = wsf + 913424;                // 491520
  // ---- dead-after-gather region (aliased by partial) ----
  float* t1      = wsf + 1404944;               // 983040
  float* h1      = wsf + 2387984;               // 122880
  float* t2t     = wsf + 2510864;               // 491520 ([px][64])
  float* params  = wsf + 3002384;               // 61440
  unsigned long long* keys = (unsigned long long*)(wsf + 3063824); // 15360 f
  float* partial = t1;  // 5*64*7680 = 2,457,600 f; ends @3,862,544 <= proven 4,158,992

  // dtype sniff + small conversions
  sniff_k<<<1, 256, 0, stream>>>((const unsigned short*)fl_w1, flag);
  cvt_k<<<30, 256, 0, stream>>>(flag, disp, dispf, 7680);
  cvt_small_k<<<1, 512, 0, stream>>>(flag, invK, Km, rot_w2, rot_b2,
                                     scl_w2, scl_b2, opa_w2, opa_b2, smallf);
  // weight repack to [ci*9+k][Cout]
  repack_w_k<<<576, 256, 0, stream>>>(flag, fl_w1, wp_fl1, 1152, 128, 128, 0);
  repack_w_k<<<288, 256, 0, stream>>>(flag, fl_w2, wp_fl2, 1152, 64, 64, 0);
  repack_w_k<<<288, 256, 0, stream>>>(flag, fr_w, wp_fr, 576, 128, 128, 0);
  repack_w_k<<<36, 256, 0, stream>>>(flag, rot_w1, wp_h1, 1152, 8, 16, 0);
  repack_w_k<<<27, 256, 0, stream>>>(flag, scl_w1, wp_h1, 1152, 6, 16, 8);
  repack_w_k<<<9, 256, 0, stream>>>(flag, opa_w1, wp_h1, 1152, 2, 16, 14);
  bias_concat_k<<<1, 512, 0, stream>>>(flag, rot_b1, scl_b1, opa_b1, fl_b1, fl_b2, fr_b, biasf);

  // heads first conv (16 ch, edge, gelu) — COB=16, PXT=2
  conv_tiled_k<true, false, false, 16, 2><<<dim3(5, 48, 1), 256, 0, stream>>>(
      init_feature, wp_h1, biasf, h1, flag, 128, 16, 0, 2);
  // gs_feat chain (reflect, elu)
  conv_tiled_k<true, false, false, 64, 8><<<dim3(5, 48, 2), 256, 0, stream>>>(
      init_feature, wp_fl1, biasf + 16, t1, flag, 128, 128, 1, 1);
  conv_tiled_k<false, false, true, 64, 8><<<dim3(5, 48, 1), 256, 0, stream>>>(
      t1, wp_fl2, biasf + 144, t2t, flag, 128, 64, 1, 1);
  // heads second conv + gaussian prep
  head2_prep_k<<<60, 128, 0, stream>>>(h1, smallf, dispf, params);
  // stable sort by depth, gather
  sort_k<<<1, 1024, 0, stream>>>(params, keys);
  gather_k<<<(NP * 64) / 256, 256, 0, stream>>>(keys, params, t2t, params_s, feat_s);
  // rasterize (chunked; partial aliases dead region) + combine
  raster_k<<<dim3(NP / 64, NCHUNK), 256, 0, stream>>>(params_s, feat_s, partial, tch);
  combine_k<<<(NP * 64) / 256, 256, 0, stream>>>(partial, tch, lev);
  // final conv (reflect, elu) -> out (dtype per flag)
  conv_tiled_k<false, true, false, 64, 8><<<dim3(5, 48, 2), 256, 0, stream>>>(
      lev, wp_fr, biasf + 208, d_out, flag, 64, 128, 1, 1);
}

// Round 4
// 834.894 us; speedup vs baseline: 1.3124x; 1.0026x over previous
//
#include <hip/hip_runtime.h>
#include <hip/hip_bf16.h>
#include <math.h>

#define Hh 48
#define Ww 160
#define NP 7680      // H*W
#define NCHUNK 12
#define CHSZ (NP / NCHUNK) // 640
#define SORTN 8192

using bf16 = __hip_bfloat16;

__device__ __forceinline__ float bfdec(unsigned short u) {
  return __uint_as_float(((unsigned)u) << 16);
}
__device__ __forceinline__ float ldany(const void* p, size_t i, int isbf) {
  return isbf ? bfdec(((const unsigned short*)p)[i]) : ((const float*)p)[i];
}

__device__ __forceinline__ int mapidx(int i, int n, int mode) {
  if (mode == 0) return i < 0 ? 0 : (i >= n ? n - 1 : i);       // edge
  return i < 0 ? -i : (i >= n ? 2 * n - 2 - i : i);             // reflect
}

__device__ __forceinline__ float act_apply(float v, int act) {
  if (act == 1) return v > 0.f ? v : expm1f(v);                  // elu
  if (act == 2) {                                                // gelu (tanh approx)
    float c = v + 0.044715f * v * v * v;
    return 0.5f * v * (1.f + tanhf(0.7978845608028654f * c));
  }
  return v;
}

// ---------------- dtype sniffer ----------------
__global__ __launch_bounds__(256) void sniff_k(const unsigned short* __restrict__ w,
                                               int* __restrict__ flag) {
  __shared__ int cnt[256];
  int c = 0;
  for (int i = threadIdx.x; i < 2048; i += 256) {
    float a = fabsf(bfdec(w[i]));
    if (a > 1e-3f && a < 0.5f) c++;
  }
  cnt[threadIdx.x] = c;
  __syncthreads();
  for (int s = 128; s > 0; s >>= 1) {
    if (threadIdx.x < s) cnt[threadIdx.x] += cnt[threadIdx.x + s];
    __syncthreads();
  }
  if (threadIdx.x == 0) flag[0] = (cnt[0] > 1536) ? 1 : 0;
}

// ---------------- merged prep: cvt + repacks + bias, one launch ----------------
// segments: disp 7680 | small 508 | bias 336 | fl1 147456 | fl2 73728 | fr 73728
//           | rot1 9216 | scl1 6912 | opa1 2304   (total 321868 -> 1258 blocks)
__global__ __launch_bounds__(256) void prep_k(const int* __restrict__ flag,
    const void* disp, const void* invK, const void* K, const void* rw2,
    const void* rb2, const void* sw2, const void* sb2, const void* ow2, const void* ob2,
    const void* rb1, const void* sb1, const void* ob1, const void* fb1, const void* fb2,
    const void* frb, const void* fl_w1, const void* fl_w2, const void* fr_w,
    const void* rot_w1, const void* scl_w1, const void* opa_w1,
    float* __restrict__ dispf, float* __restrict__ smallf, float* __restrict__ biasf,
    float* __restrict__ wp_fl1, float* __restrict__ wp_fl2, float* __restrict__ wp_fr,
    float* __restrict__ wp_h1) {
  int i = blockIdx.x * 256 + threadIdx.x;
  int f = *flag;
  if (i < 7680) { dispf[i] = ldany(disp, i, f); return; }
  i -= 7680;
  if (i < 508) {
    // invK@0(16) K@16(16) rw2@32(288) rb2@320(4) sw2@324(162) sb2@486(3) ow2@489(18) ob2@507(1)
    const void* src; int off;
    if (i < 16)       { src = invK; off = i; }
    else if (i < 32)  { src = K;    off = i - 16; }
    else if (i < 320) { src = rw2;  off = i - 32; }
    else if (i < 324) { src = rb2;  off = i - 320; }
    else if (i < 486) { src = sw2;  off = i - 324; }
    else if (i < 489) { src = sb2;  off = i - 486; }
    else if (i < 507) { src = ow2;  off = i - 489; }
    else              { src = ob2;  off = i - 507; }
    smallf[i] = ldany(src, off, f); return;
  }
  i -= 508;
  if (i < 336) {
    // [0,16) head1 (rot8,scl6,opa2); [16,144) fl_b1; [144,208) fl_b2; [208,336) fr_b
    if (i < 8) biasf[i] = ldany(rb1, i, f);
    else if (i < 14) biasf[i] = ldany(sb1, i - 8, f);
    else if (i < 16) biasf[i] = ldany(ob1, i - 14, f);
    else if (i < 144) biasf[i] = ldany(fb1, i - 16, f);
    else if (i < 208) biasf[i] = ldany(fb2, i - 144, f);
    else biasf[i] = ldany(frb, i - 208, f);
    return;
  }
  i -= 336;
  if (i < 147456) { int co = i / 1152, rem = i - co * 1152;
    wp_fl1[(size_t)rem * 128 + co] = ldany(fl_w1, i, f); return; }
  i -= 147456;
  if (i < 73728) { int co = i / 1152, rem = i - co * 1152;
    wp_fl2[(size_t)rem * 64 + co] = ldany(fl_w2, i, f); return; }
  i -= 73728;
  if (i < 73728) { int co = i / 576, rem = i - co * 576;
    wp_fr[(size_t)rem * 128 + co] = ldany(fr_w, i, f); return; }
  i -= 73728;
  if (i < 9216) { int co = i / 1152, rem = i - co * 1152;
    wp_h1[(size_t)rem * 16 + co] = ldany(rot_w1, i, f); return; }
  i -= 9216;
  if (i < 6912) { int co = i / 1152, rem = i - co * 1152;
    wp_h1[(size_t)rem * 16 + 8 + co] = ldany(scl_w1, i, f); return; }
  i -= 6912;
  if (i < 2304) { int co = i / 1152, rem = i - co * 1152;
    wp_h1[(size_t)rem * 16 + 14 + co] = ldany(opa_w1, i, f); return; }
}

// ---------------- tiled direct 3x3 conv ----------------
// block 256 = COB couts x (256/COB) w-groups of PXT px; tile = 32 w, 1 h
// weights: [ci*9+k][Cout] (lane-coalesced). grid (5, 48, Cout/COB)
template<bool FIRST, bool FINAL, bool TRANS, int COB, int PXT>
__global__ __launch_bounds__(256) void conv_tiled_k(const void* __restrict__ xv,
    const float* __restrict__ wp, const float* __restrict__ bias, void* __restrict__ out,
    const int* __restrict__ flag, int Cin, int Cout, int padmode, int act) {
  __shared__ float sx[8][3][36];
  const int h = blockIdx.y;
  const int w0 = blockIdx.x * 32;
  const int coL = threadIdx.x & (COB - 1);
  const int co = blockIdx.z * COB + coL;
  const int wg = threadIdx.x / COB;
  const int wl = wg * PXT;
  const int isbf = FIRST ? *flag : 0;
  float acc[PXT];
#pragma unroll
  for (int i = 0; i < PXT; i++) acc[i] = 0.f;
  int rows[3];
#pragma unroll
  for (int r = 0; r < 3; r++) rows[r] = mapidx(h + r - 1, Hh, padmode);
  for (int ci0 = 0; ci0 < Cin; ci0 += 8) {
    __syncthreads();
    for (int idx = threadIdx.x; idx < 816; idx += 256) {
      int ci = idx / 102; int rem = idx - ci * 102;
      int r = rem / 34;   int wi = rem - r * 34;
      int wwg = mapidx(w0 + wi - 1, Ww, padmode);
      sx[ci][r][wi] = ldany(xv, ((size_t)(ci0 + ci) * Hh + rows[r]) * Ww + wwg, isbf);
    }
    __syncthreads();
#pragma unroll
    for (int ci = 0; ci < 8; ci++) {
      float wk[9];
      const float* wb = wp + (size_t)((ci0 + ci) * 9) * Cout + co;
#pragma unroll
      for (int k = 0; k < 9; k++) wk[k] = wb[(size_t)k * Cout];
#pragma unroll
      for (int r = 0; r < 3; r++) {
        float rv[PXT + 2];
        if constexpr (PXT == 8) {
          const float4* sv = (const float4*)&sx[ci][r][0];
          float4 a = sv[wl / 4], b = sv[wl / 4 + 1], c = sv[wl / 4 + 2];
          rv[0]=a.x; rv[1]=a.y; rv[2]=a.z; rv[3]=a.w;
          rv[4]=b.x; rv[5]=b.y; rv[6]=b.z; rv[7]=b.w;
          rv[8]=c.x; rv[9]=c.y;
        } else {
#pragma unroll
          for (int q = 0; q < PXT + 2; q++) rv[q] = sx[ci][r][wl + q];
        }
#pragma unroll
        for (int pxi = 0; pxi < PXT; pxi++)
          acc[pxi] = fmaf(wk[r * 3], rv[pxi],
                     fmaf(wk[r * 3 + 1], rv[pxi + 1],
                     fmaf(wk[r * 3 + 2], rv[pxi + 2], acc[pxi])));
      }
    }
  }
  {
    float bv = bias[co];
    int obf = FINAL ? *flag : 0;
#pragma unroll
    for (int pxi = 0; pxi < PXT; pxi++) {
      float v = act_apply(acc[pxi] + bv, act);
      if (TRANS) {
        ((float*)out)[(size_t)(h * Ww + w0 + wl + pxi) * 64 + co] = v;
      } else {
        size_t oi = ((size_t)co * Hh + h) * Ww + w0 + wl + pxi;
        if (FINAL && obf) ((bf16*)out)[oi] = __float2bfloat16(v);
        else ((float*)out)[oi] = v;
      }
    }
  }
}

// ---------------- head2 + per-gaussian prep ----------------
__global__ __launch_bounds__(128) void head2_prep_k(const float* __restrict__ h1,
    const float* __restrict__ smallf, const float* __restrict__ dispf,
    float* __restrict__ params) {
  const float* invK = smallf;
  const float* Km   = smallf + 16;
  const float* rw2  = smallf + 32;
  const float* rb2  = smallf + 320;
  const float* sw2  = smallf + 324;
  const float* sb2  = smallf + 486;
  const float* ow2  = smallf + 489;
  const float* ob2  = smallf + 507;
  int p = blockIdx.x * 128 + threadIdx.x;
  if (p >= NP) return;
  int hh = p / Ww, ww = p - hh * Ww;
  float racc[4], sacc[3], oacc;
#pragma unroll
  for (int i = 0; i < 4; i++) racc[i] = rb2[i];
#pragma unroll
  for (int i = 0; i < 3; i++) sacc[i] = sb2[i];
  oacc = ob2[0];
  for (int ci = 0; ci < 16; ci++) {
    float t9[9];
#pragma unroll
    for (int r = 0; r < 3; r++) {
      int rr = mapidx(hh + r - 1, Hh, 0);
#pragma unroll
      for (int s = 0; s < 3; s++) {
        int cc = mapidx(ww + s - 1, Ww, 0);
        t9[r * 3 + s] = h1[(size_t)ci * NP + rr * Ww + cc];
      }
    }
    if (ci < 8) {
      for (int co = 0; co < 4; co++)
#pragma unroll
        for (int k = 0; k < 9; k++)
          racc[co] = fmaf(t9[k], rw2[(co * 8 + ci) * 9 + k], racc[co]);
    } else if (ci < 14) {
      int c2 = ci - 8;
      for (int co = 0; co < 3; co++)
#pragma unroll
        for (int k = 0; k < 9; k++)
          sacc[co] = fmaf(t9[k], sw2[(co * 6 + c2) * 9 + k], sacc[co]);
    } else {
      int c2 = ci - 14;
#pragma unroll
      for (int k = 0; k < 9; k++)
        oacc = fmaf(t9[k], ow2[c2 * 9 + k], oacc);
    }
  }
  float nq = sqrtf(racc[0]*racc[0] + racc[1]*racc[1] + racc[2]*racc[2] + racc[3]*racc[3]);
  nq = fmaxf(nq, 1e-12f);
  float qw = racc[0] / nq, qx = racc[1] / nq, qy = racc[2] / nq, qz = racc[3] / nq;
  float s0 = fabsf(sacc[0]), s1 = fabsf(sacc[1]), s2 = fabsf(sacc[2]);
  float opa = 1.f / (1.f + __expf(-oacc));
  float d = dispf[p];
  float scaled = 0.01f + 9.99f * d;
  float depth = fminf(fmaxf(1.f / scaled, 0.1f), 100.f);
  float M00 = invK[0], M01 = invK[1], M02 = invK[2];
  float M10 = invK[4], M11 = invK[5], M12 = invK[6];
  float M20 = invK[8], M21 = invK[9], M22 = invK[10];
  float gxf = (float)ww, gyf = (float)hh;
  float X = (M00 * gxf + M01 * gyf + M02) * depth;
  float Y = (M10 * gxf + M11 * gyf + M12) * depth;
  float Z = (M20 * gxf + M21 * gyf + M22) * depth;
  float fxk = Km[0], fyk = Km[5];
  float cxk = Km[2], cyk = Km[6];
  float u = fxk * X / Z + cxk;
  float v = fyk * Y / Z + cyk;
  float R00 = 1.f - 2.f*(qy*qy + qz*qz), R01 = 2.f*(qx*qy - qw*qz), R02 = 2.f*(qx*qz + qw*qy);
  float R10 = 2.f*(qx*qy + qw*qz), R11 = 1.f - 2.f*(qx*qx + qz*qz), R12 = 2.f*(qy*qz - qw*qx);
  float R20 = 2.f*(qx*qz - qw*qy), R21 = 2.f*(qy*qz + qw*qx), R22 = 1.f - 2.f*(qx*qx + qy*qy);
  float M0a = R00*s0, M0b = R01*s1, M0c = R02*s2;
  float M1a = R10*s0, M1b = R11*s1, M1c = R12*s2;
  float M2a = R20*s0, M2b = R21*s1, M2c = R22*s2;
  float S00 = M0a*M0a + M0b*M0b + M0c*M0c;
  float S01 = M0a*M1a + M0b*M1b + M0c*M1c;
  float S02 = M0a*M2a + M0b*M2b + M0c*M2c;
  float S11 = M1a*M1a + M1b*M1b + M1c*M1c;
  float S12 = M1a*M2a + M1b*M2b + M1c*M2c;
  float S22 = M2a*M2a + M2b*M2b + M2c*M2c;
  float iz = 1.f / Z;
  float j00 = fxk * iz, j02 = -fxk * X * iz * iz;
  float j11 = fyk * iz, j12 = -fyk * Y * iz * iz;
  float c00 = j00*j00*S00 + 2.f*j00*j02*S02 + j02*j02*S22 + 0.3f;
  float c01 = j00*j11*S01 + j00*j12*S02 + j02*j11*S12 + j02*j12*S22;
  float c11 = j11*j11*S11 + 2.f*j11*j12*S12 + j12*j12*S22 + 0.3f;
  float det = c00 * c11 - c01 * c01;
  float idet = 1.f / det;
  float* pr = params + (size_t)p * 8;
  pr[0] = u; pr[1] = v; pr[2] = c11 * idet; pr[3] = -c01 * idet;
  pr[4] = c00 * idet; pr[5] = opa; pr[6] = Z; pr[7] = 0.f;
}

// ---------------- bitonic stable sort by z ----------------
__global__ __launch_bounds__(1024) void sort_k(const float* __restrict__ params,
                                               unsigned long long* __restrict__ keys) {
  __shared__ unsigned long long sk[SORTN];
  int tid = threadIdx.x;
  for (int i = tid; i < SORTN; i += 1024) {
    if (i < NP) {
      unsigned zu = __float_as_uint(params[(size_t)i * 8 + 6]);
      sk[i] = ((unsigned long long)zu << 32) | (unsigned)i;
    } else sk[i] = ~0ULL;
  }
  __syncthreads();
  for (int k = 2; k <= SORTN; k <<= 1) {
    for (int j = k >> 1; j > 0; j >>= 1) {
      for (int i = tid; i < SORTN; i += 1024) {
        int l = i ^ j;
        if (l > i) {
          unsigned long long a = sk[i], b = sk[l];
          bool up = ((i & k) == 0);
          if ((a > b) == up) { sk[i] = b; sk[l] = a; }
        }
      }
      __syncthreads();
    }
  }
  for (int i = tid; i < NP; i += 1024) keys[i] = sk[i];
}

// ---------------- gather into sorted order + zero lev ----------------
__global__ __launch_bounds__(256) void gather_k(const unsigned long long* __restrict__ keys,
    const float* __restrict__ params, const float* __restrict__ t2t,
    float* __restrict__ params_s, float* __restrict__ feat_s, float* __restrict__ lev) {
  int gid = blockIdx.x * 256 + threadIdx.x;   // NP*64
  int n = gid >> 6, c = gid & 63;
  int orig = (int)(keys[n] & 0xFFFFFFFFu);
  feat_s[gid] = t2t[((size_t)orig << 6) + c];
  lev[gid] = 0.f;
  if (c < 8) params_s[(n << 3) + c] = params[((size_t)orig << 3) + c];
}

// ---------------- pass A: per-chunk transmittance only ----------------
// grid (NP/256, NCHUNK), block 256 (4 waves x 64 px)
__global__ __launch_bounds__(256) void alpha_k(const float* __restrict__ params_s,
    float* __restrict__ tch) {
  const int p = blockIdx.x * 256 + threadIdx.x;
  const int ch = blockIdx.y;
  const float px = (float)(p % Ww), py = (float)(p / Ww);
  float T = 1.f;
  const int g0 = ch * CHSZ;
  for (int n = g0; n < g0 + CHSZ; n++) {
    const float4* pv = (const float4*)(params_s + ((size_t)n << 3));  // uniform addr
    float4 pa = pv[0], pb = pv[1];
    float dx = px - pa.x, dy = py - pa.y;
    float power = -0.5f * (pa.z * dx * dx + pb.x * dy * dy) - pa.w * dx * dy;
    if (__any(power > -18.f)) {   // alpha<2^-25 rounds T*(1-a) to T exactly
      float al = (power <= 0.f) ? fminf(pb.y * __expf(power), 0.99f) : 0.f;
      T *= 1.f - al;
    }
  }
  tch[(size_t)ch * NP + p] = T;
}

// ---------------- pass B: features, seeded by prefix transmittance ----------------
// grid (NP/128, NCHUNK), block 128 (2 waves x 64 px); one wave owns all 64 feats
__global__ __launch_bounds__(128) void raster_k(const float* __restrict__ params_s,
    const float* __restrict__ feat_s, const float* __restrict__ tch,
    float* __restrict__ lev) {
  const int p = blockIdx.x * 128 + threadIdx.x;
  const int ch = blockIdx.y;
  float Ts = 1.f;
  for (int c = 0; c < ch; c++) Ts *= tch[(size_t)c * NP + p];
  const float px = (float)(p % Ww), py = (float)(p / Ww);
  float4 acc[16];
#pragma unroll
  for (int q = 0; q < 16; q++) acc[q] = make_float4(0.f, 0.f, 0.f, 0.f);
  float T = 1.f;
  const int g0 = ch * CHSZ;
  for (int n = g0; n < g0 + CHSZ; n++) {
    const float4* pv = (const float4*)(params_s + ((size_t)n << 3));  // uniform addr
    float4 pa = pv[0], pb = pv[1];
    float dx = px - pa.x, dy = py - pa.y;
    float power = -0.5f * (pa.z * dx * dx + pb.x * dy * dy) - pa.w * dx * dy;
    if (__any(power > -18.f)) {
      float al = (power <= 0.f) ? fminf(pb.y * __expf(power), 0.99f) : 0.f;
      float wgt = al * T;
      T *= 1.f - al;
      if (__any(wgt > 1e-12f)) {
        const float4* fr = (const float4*)(feat_s + ((size_t)n << 6));  // uniform addr
#pragma unroll
        for (int q = 0; q < 16; q++) {
          float4 f = fr[q];
          acc[q].x = fmaf(wgt, f.x, acc[q].x);
          acc[q].y = fmaf(wgt, f.y, acc[q].y);
          acc[q].z = fmaf(wgt, f.z, acc[q].z);
          acc[q].w = fmaf(wgt, f.w, acc[q].w);
        }
      }
    }
  }
#pragma unroll
  for (int q = 0; q < 16; q++) {
    atomicAdd(&lev[(size_t)(q * 4 + 0) * NP + p], Ts * acc[q].x);
    atomicAdd(&lev[(size_t)(q * 4 + 1) * NP + p], Ts * acc[q].y);
    atomicAdd(&lev[(size_t)(q * 4 + 2) * NP + p], Ts * acc[q].z);
    atomicAdd(&lev[(size_t)(q * 4 + 3) * NP + p], Ts * acc[q].w);
  }
}

extern "C" void kernel_launch(void* const* d_in, const int* in_sizes, int n_in,
                              void* d_out, int out_size, void* d_ws, size_t ws_size,
                              hipStream_t stream) {
  (void)in_sizes; (void)n_in; (void)out_size; (void)ws_size;
  const void* init_feature = d_in[0];
  const void* disp   = d_in[1];
  const void* invK   = d_in[2];
  const void* Km     = d_in[3];
  const void* rot_w1 = d_in[4];
  const void* rot_b1 = d_in[5];
  const void* rot_w2 = d_in[6];
  const void* rot_b2 = d_in[7];
  const void* scl_w1 = d_in[8];
  const void* scl_b1 = d_in[9];
  const void* scl_w2 = d_in[10];
  const void* scl_b2 = d_in[11];
  const void* opa_w1 = d_in[12];
  const void* opa_b1 = d_in[13];
  const void* opa_w2 = d_in[14];
  const void* opa_b2 = d_in[15];
  const void* fl_w1  = d_in[16];
  const void* fl_b1  = d_in[17];
  const void* fl_w2  = d_in[18];
  const void* fl_b2  = d_in[19];
  const void* fr_w   = d_in[20];
  const void* fr_b   = d_in[21];

  float* wsf = (float*)d_ws;
  // layout (floats); total 3,132,944 f = 12.53 MB (< 16.6 MB proven in R1)
  int*   flag    = (int*)wsf;                   // @0        16
  float* smallf  = wsf + 16;                    // 512
  float* dispf   = wsf + 528;                   // 7680
  float* biasf   = wsf + 8208;                  // 512
  float* wp_h1   = wsf + 8720;                  // 18432
  float* wp_fl1  = wsf + 27152;                 // 147456
  float* wp_fl2  = wsf + 174608;                // 73728
  float* wp_fr   = wsf + 248336;                // 73728
  float* params_s= wsf + 322064;                // 61440
  float* feat_s  = wsf + 383504;                // 491520
  float* tch     = wsf + 875024;                // 12*7680 = 92160
  float* lev     = wsf + 967184;                // 491520
  float* t1      = wsf + 1458704;               // 983040
  float* h1      = wsf + 2441744;               // 122880
  float* t2t     = wsf + 2564624;               // 491520 ([px][64])
  float* params  = wsf + 3056144;               // 61440
  unsigned long long* keys = (unsigned long long*)(wsf + 3117584); // 15360 f

  // dtype sniff, then one merged prep launch
  sniff_k<<<1, 256, 0, stream>>>((const unsigned short*)fl_w1, flag);
  prep_k<<<1258, 256, 0, stream>>>(flag,
      disp, invK, Km, rot_w2, rot_b2, scl_w2, scl_b2, opa_w2, opa_b2,
      rot_b1, scl_b1, opa_b1, fl_b1, fl_b2, fr_b,
      fl_w1, fl_w2, fr_w, rot_w1, scl_w1, opa_w1,
      dispf, smallf, biasf, wp_fl1, wp_fl2, wp_fr, wp_h1);

  // heads first conv (16 ch, edge, gelu)
  conv_tiled_k<true, false, false, 16, 2><<<dim3(5, 48, 1), 256, 0, stream>>>(
      init_feature, wp_h1, biasf, h1, flag, 128, 16, 0, 2);
  // gs_feat chain (reflect, elu)
  conv_tiled_k<true, false, false, 64, 8><<<dim3(5, 48, 2), 256, 0, stream>>>(
      init_feature, wp_fl1, biasf + 16, t1, flag, 128, 128, 1, 1);
  conv_tiled_k<false, false, true, 64, 8><<<dim3(5, 48, 1), 256, 0, stream>>>(
      t1, wp_fl2, biasf + 144, t2t, flag, 128, 64, 1, 1);
  // heads second conv + gaussian prep
  head2_prep_k<<<60, 128, 0, stream>>>(h1, smallf, dispf, params);
  // stable sort by depth, gather (+ zero lev)
  sort_k<<<1, 1024, 0, stream>>>(params, keys);
  gather_k<<<(NP * 64) / 256, 256, 0, stream>>>(keys, params, t2t, params_s, feat_s, lev);
  // two-pass raster: chunk transmittances, then features + atomic combine
  alpha_k<<<dim3(NP / 256, NCHUNK), 256, 0, stream>>>(params_s, tch);
  raster_k<<<dim3(NP / 128, NCHUNK), 128, 0, stream>>>(params_s, feat_s, tch, lev);
  // final conv (reflect, elu) -> out (dtype per flag)
  conv_tiled_k<false, true, false, 64, 8><<<dim3(5, 48, 2), 256, 0, stream>>>(
      lev, wp_fr, biasf + 208, d_out, flag, 64, 128, 1, 1);
}